// Round 4
// baseline (31.951 us; speedup 1.0000x reference)
//
#include <hip/hip_runtime.h>
#include <hip/hip_bf16.h>

// out[b,y,x,o] = 64 * sum_c in[b, y/2, x/2, c], B=32,H=64,W=64,C=64,KH=KW=2
// Input 33.5 MB, Output 134.2 MB.
// R3: split read-phase and write-phase into two kernels to avoid HBM
// read/write turnaround on mixed streams (single fused kernel sustained
// 5.67 TB/s; pure-write fill sustains ~6.9 TB/s).
//   reduce: in (33.5MB) -> sums (512KB in d_ws)      [read-bound, ~5.4us]
//   bcast : sums (512KB, L2) -> out (134MB)          [write-bound, ~19.7us]

typedef float f32x4 __attribute__((ext_vector_type(4)));

// ---- Kernel 1: per-input-row channel sums, scaled by C=64 ----
__global__ __launch_bounds__(256) void reduce_kernel(
    const float* __restrict__ in, float* __restrict__ sums) {
    const int bid = blockIdx.x;          // bid = b*64 + h
    const int t   = threadIdx.x;
    __shared__ float s[64];

    const f32x4* in4 = reinterpret_cast<const f32x4*>(in) + (size_t)bid * 1024;
    float partial[4];
#pragma unroll
    for (int j = 0; j < 4; ++j) {
        f32x4 v = in4[t + 256 * j];      // coalesced 16KB/block
        partial[j] = (v.x + v.y) + (v.z + v.w);
    }
    // f4 index i = t + 256j belongs to pixel p = t/16 + 16j; 16-lane reduce.
#pragma unroll
    for (int j = 0; j < 4; ++j) {
#pragma unroll
        for (int m = 1; m < 16; m <<= 1)
            partial[j] += __shfl_xor(partial[j], m);
    }
    if ((t & 15) == 0) {
        const int g = t >> 4;
#pragma unroll
        for (int j = 0; j < 4; ++j)
            s[g + 16 * j] = partial[j] * 64.0f;   // ×C
    }
    __syncthreads();
    if (t < 64) sums[bid * 64 + t] = s[t];        // coalesced 256B/block
}

// ---- Kernel 2: pure broadcast-write of two output rows per block ----
__global__ __launch_bounds__(256) void bcast_kernel(
    const float* __restrict__ sums, float* __restrict__ out) {
    const int bid = blockIdx.x;          // bid = b*64 + h
    const int t   = threadIdx.x;
    __shared__ float s[64];
    if (t < 64) s[t] = sums[bid * 64 + t];
    __syncthreads();

    const int b = bid >> 6;
    const int h = bid & 63;
    f32x4* out4 = reinterpret_cast<f32x4*>(out);
    const size_t row0 = (size_t)(b * 128 + 2 * h) * 2048;   // 2048 f4 per row

#pragma unroll
    for (int k = 0; k < 8; ++k) {
        const int i = t + 256 * k;
        const float v = s[i >> 5];       // 32-lane LDS broadcast
        f32x4 val = {v, v, v, v};
        out4[row0 + i]        = val;     // row y = 2h   (contiguous 64KB/block)
        out4[row0 + 2048 + i] = val;     // row y = 2h+1
    }
}

// ---- Fallback: proven fused single-kernel (R0), if ws too small ----
__global__ __launch_bounds__(256) void fused_kernel(
    const float* __restrict__ in, float* __restrict__ out) {
    const int bid = blockIdx.x;
    const int t   = threadIdx.x;
    __shared__ float s[64];
    const f32x4* in4 = reinterpret_cast<const f32x4*>(in) + (size_t)bid * 1024;
    float partial[4];
#pragma unroll
    for (int j = 0; j < 4; ++j) {
        f32x4 v = in4[t + 256 * j];
        partial[j] = (v.x + v.y) + (v.z + v.w);
    }
#pragma unroll
    for (int j = 0; j < 4; ++j) {
#pragma unroll
        for (int m = 1; m < 16; m <<= 1)
            partial[j] += __shfl_xor(partial[j], m);
    }
    if ((t & 15) == 0) {
        const int g = t >> 4;
#pragma unroll
        for (int j = 0; j < 4; ++j)
            s[g + 16 * j] = partial[j] * 64.0f;
    }
    __syncthreads();
    const int b = bid >> 6;
    const int h = bid & 63;
    f32x4* out4 = reinterpret_cast<f32x4*>(out);
    const size_t row0 = (size_t)(b * 128 + 2 * h) * 2048;
#pragma unroll
    for (int k = 0; k < 8; ++k) {
        const int i = t + 256 * k;
        const float v = s[i >> 5];
        f32x4 val = {v, v, v, v};
        out4[row0 + i]        = val;
        out4[row0 + 2048 + i] = val;
    }
}

extern "C" void kernel_launch(void* const* d_in, const int* in_sizes, int n_in,
                              void* d_out, int out_size, void* d_ws, size_t ws_size,
                              hipStream_t stream) {
    const float* in = (const float*)d_in[0];
    float* out = (float*)d_out;
    const size_t need = 2048u * 64u * sizeof(float);   // 512 KB of sums
    if (ws_size >= need && d_ws != nullptr) {
        float* sums = (float*)d_ws;
        reduce_kernel<<<2048, 256, 0, stream>>>(in, sums);
        bcast_kernel<<<2048, 256, 0, stream>>>(sums, out);
    } else {
        fused_kernel<<<2048, 256, 0, stream>>>(in, out);
    }
}

// Round 5
// 29.982 us; speedup vs baseline: 1.0657x; 1.0657x over previous
//
#include <hip/hip_runtime.h>
#include <hip/hip_bf16.h>

// out[b,y,x,o] = 64 * sum_c in[b, y/2, x/2, c], B=32,H=64,W=64,C=64,KH=KW=2
// Input 33.5 MB, Output 134.2 MB. HBM-bound; traffic already minimal.
// R4: wave-autonomous — no LDS, no __syncthreads. Each wave owns 16 input
// pixels: 16-lane xor-butterfly reduce (sum lands in ALL lanes of the group),
// then per-store-iteration __shfl redistributes. Waves overlap load/store
// phases independently; removes the all-waves barrier bubble of R0.
// (R1/R2 nt-hints: regressed. R3 two-kernel split: regressed. R0: 29.57us.)

typedef float f32x4 __attribute__((ext_vector_type(4)));

__global__ __launch_bounds__(256) void Conv2DTransposeNN_kernel(
    const float* __restrict__ in, float* __restrict__ out) {
    const int bid = blockIdx.x;          // bid = b*64 + h
    const int t   = threadIdx.x;
    const int w   = t >> 6;              // wave 0..3: owns pixels [16w,16w+16)
    const int l   = t & 63;

    // ---- load: wave w reads f4 range [256w, 256w+256) of its input row ----
    const f32x4* in4 = reinterpret_cast<const f32x4*>(in)
                       + (size_t)bid * 1024 + 256 * w;
    float partial[4];
#pragma unroll
    for (int j = 0; j < 4; ++j) {
        f32x4 v = in4[l + 64 * j];       // coalesced 1KB/instr
        partial[j] = (v.x + v.y) + (v.z + v.w);
    }
    // f4 idx 256w+l+64j -> pixel 16w + (l>>4) + 4j: reduce over the 16-lane
    // group sharing l>>4; butterfly leaves the sum in every lane of the group.
#pragma unroll
    for (int j = 0; j < 4; ++j) {
#pragma unroll
        for (int m = 1; m < 16; m <<= 1)
            partial[j] += __shfl_xor(partial[j], m);
        partial[j] *= 64.0f;             // ×C
    }

    // ---- store: two output rows, wave region = pixels [16w,16w+16) ----
    const int b = bid >> 6;
    const int h = bid & 63;
    f32x4* out4 = reinterpret_cast<f32x4*>(out);
    // 2048 f4 per output row; wave's slice starts at 512w
    const size_t row0 = (size_t)(b * 128 + 2 * h) * 2048 + 512 * w;

#pragma unroll
    for (int m = 0; m < 8; ++m) {
        // store f4 o = 512w + 64m + l -> pixel 16w + 2m + (l>>5)
        const int j = m >> 1;                    // uniform & static per m
        const int g = (2 * m + (l >> 5)) & 3;    // source 16-lane group
        const float v = __shfl(partial[j], g * 16 + (l & 15));
        f32x4 val = {v, v, v, v};
        out4[row0 + 64 * m + l]        = val;    // row y = 2h
        out4[row0 + 2048 + 64 * m + l] = val;    // row y = 2h+1
    }
}

extern "C" void kernel_launch(void* const* d_in, const int* in_sizes, int n_in,
                              void* d_out, int out_size, void* d_ws, size_t ws_size,
                              hipStream_t stream) {
    const float* in = (const float*)d_in[0];
    float* out = (float*)d_out;
    Conv2DTransposeNN_kernel<<<2048, 256, 0, stream>>>(in, out);
}